// Round 1
// baseline (14962.117 us; speedup 1.0000x reference)
//
#include <hip/hip_runtime.h>
#include <stdint.h>

// ---------------------------------------------------------------------------
// LstmAtt: 128-step LSTM+attention recurrence, B=1024, H=768, D_IN=130, L=128.
// Round-1 design: correctness-first with split-bf16 (hi+lo) MFMA GEMMs
// (3-term product => ~fp32 accuracy), fp32 softmax / v-sum / LSTM / head.
// Act buffer layout per row (K = 1184 halfs): [0..389]=v (3*130), [390..415]=0 pad
// (16B alignment for the h sub-GEMM), [416..1183]=h (768).
// ---------------------------------------------------------------------------

#define B_SZ   1024
#define LSEQ   128
#define DIN    130
#define HDIM   768
#define NFEAT  49
#define NPROJ  40
#define KPAD   1184
#define VOFF   416
#define NGATE  3072

typedef unsigned short u16;
typedef __attribute__((ext_vector_type(8))) short short8;
typedef __attribute__((ext_vector_type(4))) float f32x4;

__device__ __forceinline__ u16 f2bf(float f) {
  unsigned int u = __float_as_uint(f);
  u += 0x7FFFu + ((u >> 16) & 1u);   // round-to-nearest-even
  return (u16)(u >> 16);
}
__device__ __forceinline__ float bf2f(u16 b) {
  return __uint_as_float(((unsigned int)b) << 16);
}
__device__ __forceinline__ void split_store(float x, u16* hi, u16* lo) {
  u16 h = f2bf(x);
  *hi = h;
  *lo = f2bf(x - bf2f(h));
}

// ---------------------------------------------------------------------------
// Split-bf16 GEMM:  C[M,N] = A[M,K] * W[N,K]^T   (both stored row-major, K-pad mult 32)
// A,W given as bf16 hi/lo pairs; 3 MFMA terms: hi*hi + lo*hi + hi*lo.
// Block = 256 thr (4 waves, 2x2), tile BM x BN, per-wave (BM/2)x(BN/2) of 16x16 frags.
// LDS row stride 40 halfs (80 B): 16B-aligned, m and m+8 alias 2-way only (free).
// mfma_f32_16x16x32_bf16 layouts (HW-verified per guide):
//   A frag: A[m=lane&15][k=quad*8+j]; B frag: W[n=lane&15][k=quad*8+j];
//   C/D:    col=lane&15, row=quad*4+reg.
// ---------------------------------------------------------------------------
template<int BM, int BN>
__global__ __launch_bounds__(256, 2) void gemm_split3(
    const u16* __restrict__ Ahi, const u16* __restrict__ Alo, int lda,
    const u16* __restrict__ Whi, const u16* __restrict__ Wlo, int ldw,
    float* __restrict__ C, int ldc, int ktiles)
{
  constexpr int FM = BM / 32;
  constexpr int FN = BN / 32;
  constexpr int STR = 40;
  __shared__ __align__(16) u16 sAh[BM * STR];
  __shared__ __align__(16) u16 sAl[BM * STR];
  __shared__ __align__(16) u16 sBh[BN * STR];
  __shared__ __align__(16) u16 sBl[BN * STR];

  const int tid  = threadIdx.x;
  const int lane = tid & 63;
  const int wid  = tid >> 6;
  const int wm   = (wid & 1) * (BM / 2);
  const int wn   = (wid >> 1) * (BN / 2);
  const int lm   = lane & 15;
  const int quad = lane >> 4;
  const long bm  = (long)blockIdx.x * BM;
  const long bn  = (long)blockIdx.y * BN;

  f32x4 acc[FM][FN];
#pragma unroll
  for (int i = 0; i < FM; ++i)
#pragma unroll
    for (int j = 0; j < FN; ++j)
      acc[i][j] = (f32x4){0.f, 0.f, 0.f, 0.f};

  for (int kt = 0; kt < ktiles; ++kt) {
    const int k0 = kt * 32;
    __syncthreads();
#pragma unroll
    for (int i = tid; i < BM * 4; i += 256) {
      const int r = i >> 2, c = (i & 3) * 8;
      const size_t g = (size_t)(bm + r) * lda + k0 + c;
      *(uint4*)&sAh[r * STR + c] = *(const uint4*)(Ahi + g);
      *(uint4*)&sAl[r * STR + c] = *(const uint4*)(Alo + g);
    }
#pragma unroll
    for (int i = tid; i < BN * 4; i += 256) {
      const int r = i >> 2, c = (i & 3) * 8;
      const size_t g = (size_t)(bn + r) * ldw + k0 + c;
      *(uint4*)&sBh[r * STR + c] = *(const uint4*)(Whi + g);
      *(uint4*)&sBl[r * STR + c] = *(const uint4*)(Wlo + g);
    }
    __syncthreads();

    short8 ah[FM], al[FM], bh[FN], bl[FN];
#pragma unroll
    for (int mi = 0; mi < FM; ++mi) {
      const int row = wm + mi * 16 + lm;
      ah[mi] = *(const short8*)&sAh[row * STR + quad * 8];
      al[mi] = *(const short8*)&sAl[row * STR + quad * 8];
    }
#pragma unroll
    for (int ni = 0; ni < FN; ++ni) {
      const int row = wn + ni * 16 + lm;
      bh[ni] = *(const short8*)&sBh[row * STR + quad * 8];
      bl[ni] = *(const short8*)&sBl[row * STR + quad * 8];
    }
#pragma unroll
    for (int mi = 0; mi < FM; ++mi)
#pragma unroll
      for (int ni = 0; ni < FN; ++ni) {
        acc[mi][ni] = __builtin_amdgcn_mfma_f32_16x16x32_bf16(ah[mi], bh[ni], acc[mi][ni], 0, 0, 0);
        acc[mi][ni] = __builtin_amdgcn_mfma_f32_16x16x32_bf16(al[mi], bh[ni], acc[mi][ni], 0, 0, 0);
        acc[mi][ni] = __builtin_amdgcn_mfma_f32_16x16x32_bf16(ah[mi], bl[ni], acc[mi][ni], 0, 0, 0);
      }
  }

#pragma unroll
  for (int mi = 0; mi < FM; ++mi)
#pragma unroll
    for (int ni = 0; ni < FN; ++ni) {
      const long col = bn + wn + ni * 16 + lm;
#pragma unroll
      for (int r = 0; r < 4; ++r) {
        const long row = bm + wm + mi * 16 + quad * 4 + r;
        C[(size_t)row * ldc + col] = acc[mi][ni][r];
      }
    }
}

// ---------------------------------------------------------------------------
// Per-sample softmax over L (x3 heads) + v = alp @ X[b]; writes v into act hi/lo.
// Block = 512 thr per sample. Phase 1: t<384 -> (k=t>>7, l=t&127). Phase 2:
// t<390 -> (k=t/130, d=t%130), column-coalesced X reads.
// ---------------------------------------------------------------------------
__global__ __launch_bounds__(512) void softmax_v(
    const float* __restrict__ logits,   // [B][384] = [b][k*128+l]
    const float* __restrict__ b_att,    // [3][128]
    const float* __restrict__ X,        // [B][128][130]
    u16* __restrict__ act_hi, u16* __restrict__ act_lo)
{
  const int b = blockIdx.x;
  const int t = threadIdx.x;
  __shared__ float s_val[384];
  __shared__ float s_red[512];

  float x = -3.4e38f;
  if (t < 384) {
    x = logits[(size_t)b * 384 + t] + b_att[t];
    s_val[t] = x;
  }
  s_red[t] = x;
  __syncthreads();
#pragma unroll
  for (int off = 64; off > 0; off >>= 1) {
    float other = -3.4e38f;
    if ((t & 127) < off) other = s_red[t + off];
    __syncthreads();
    if ((t & 127) < off) s_red[t] = fmaxf(s_red[t], other);
    __syncthreads();
  }
  const float mk = s_red[t & ~127];
  __syncthreads();

  float e = 0.f;
  if (t < 384) e = expf(s_val[t] - mk);
  s_red[t] = e;
  __syncthreads();
#pragma unroll
  for (int off = 64; off > 0; off >>= 1) {
    float other = 0.f;
    if ((t & 127) < off) other = s_red[t + off];
    __syncthreads();
    if ((t & 127) < off) s_red[t] += other;
    __syncthreads();
  }
  const float sk = s_red[t & ~127];
  if (t < 384) s_val[t] = e / sk;     // normalized alp
  __syncthreads();

  if (t < 390) {
    const int k = t / 130;
    const int d = t - k * 130;
    const float* __restrict__ Xb = X + (size_t)b * LSEQ * DIN + d;
    const float* __restrict__ ak = s_val + k * 128;
    float acc = 0.f;
#pragma unroll 8
    for (int l = 0; l < LSEQ; ++l) acc += ak[l] * Xb[(size_t)l * DIN];
    const size_t o = (size_t)b * KPAD + t;   // col = k*130+d = t
    split_store(acc, &act_hi[o], &act_lo[o]);
  }
}

// ---------------------------------------------------------------------------
// LSTM pointwise: gates [B][3072] (i,f,g,o) + biases -> c,h update; running max;
// writes h into act hi/lo at column VOFF.
// ---------------------------------------------------------------------------
__global__ __launch_bounds__(256) void lstm_update(
    const float* __restrict__ gates,
    const float* __restrict__ b_ih, const float* __restrict__ b_hh,
    float* __restrict__ cst, float* __restrict__ hmax,
    u16* __restrict__ act_hi, u16* __restrict__ act_lo)
{
  const int idx = blockIdx.x * 256 + threadIdx.x;       // B*H
  const int b = idx / HDIM;
  const int j = idx - b * HDIM;
  const float* g = gates + (size_t)b * NGATE;
  const float gi = g[j]        + b_ih[j]        + b_hh[j];
  const float gf = g[768 + j]  + b_ih[768 + j]  + b_hh[768 + j];
  const float gg = g[1536 + j] + b_ih[1536 + j] + b_hh[1536 + j];
  const float go = g[2304 + j] + b_ih[2304 + j] + b_hh[2304 + j];
  const float si = 1.f / (1.f + expf(-gi));
  const float sf = 1.f / (1.f + expf(-gf));
  const float so = 1.f / (1.f + expf(-go));
  const float cn = sf * cst[idx] + si * tanhf(gg);
  const float hn = so * tanhf(cn);
  cst[idx] = cn;
  hmax[idx] = fmaxf(hmax[idx], hn);
  const size_t o = (size_t)b * KPAD + VOFF + j;
  split_store(hn, &act_hi[o], &act_lo[o]);
}

// ---------------------------------------------------------------------------
// Final head (once): y=relu(hmax@Wd1^T+b); r1/r2=leaky(.@Wr^T+b); a=softmax(tanh(r)@Wa);
// s=relu(a0*r1+a1*r2); out=s@Wd2^T+b. One 64-thread block per sample (tiny).
// ---------------------------------------------------------------------------
__global__ __launch_bounds__(64) void final_head(
    const float* __restrict__ hmax, const float* __restrict__ Fe,
    const float* __restrict__ W_d1, const float* __restrict__ b_d1,
    const float* __restrict__ W_r,  const float* __restrict__ b_r,
    const float* __restrict__ W_a,
    const float* __restrict__ W_d2, const float* __restrict__ b_d2,
    float* __restrict__ out)
{
  const int b = blockIdx.x;
  const int t = threadIdx.x;
  __shared__ float sx[HDIM];
  __shared__ float sy[NFEAT];
  __shared__ float sr1[NPROJ], sr2[NPROJ];
  __shared__ float sa[2];

  for (int i = t; i < HDIM; i += 64) sx[i] = hmax[(size_t)b * HDIM + i];
  __syncthreads();

  if (t < NFEAT) {
    float acc = b_d1[t];
    const float* w = W_d1 + (size_t)t * HDIM;
    for (int i = 0; i < HDIM; ++i) acc += sx[i] * w[i];
    sy[t] = fmaxf(acc, 0.f);
  }
  __syncthreads();

  if (t < NPROJ) {
    float a1 = b_r[t], a2 = b_r[t];
    const float* w  = W_r + (size_t)t * NFEAT;
    const float* fe = Fe + (size_t)b * NFEAT;
    for (int i = 0; i < NFEAT; ++i) { a1 += sy[i] * w[i]; a2 += fe[i] * w[i]; }
    sr1[t] = (a1 > 0.f) ? a1 : 0.01f * a1;   // jax.nn.leaky_relu default slope
    sr2[t] = (a2 > 0.f) ? a2 : 0.01f * a2;
  }
  __syncthreads();

  if (t == 0) {
    float a1 = 0.f, a2 = 0.f;
    for (int p = 0; p < NPROJ; ++p) {
      a1 += tanhf(sr1[p]) * W_a[p];
      a2 += tanhf(sr2[p]) * W_a[p];
    }
    const float mx = fmaxf(a1, a2);
    const float e1 = expf(a1 - mx), e2 = expf(a2 - mx);
    sa[0] = e1 / (e1 + e2);
    sa[1] = e2 / (e1 + e2);
  }
  __syncthreads();

  if (t < 2) {
    float acc = b_d2[t];
    const float* w = W_d2 + (size_t)t * NPROJ;
    for (int p = 0; p < NPROJ; ++p) {
      float s = sa[0] * sr1[p] + sa[1] * sr2[p];
      s = fmaxf(s, 0.f);
      acc += s * w[p];
    }
    out[(size_t)b * 2 + t] = acc;
  }
}

// ---------------------------------------------------------------------------
// Setup kernels (run every launch; ws is re-poisoned by the harness).
// ---------------------------------------------------------------------------
__global__ __launch_bounds__(256) void pack_wcat(
    const float* __restrict__ W_ih, const float* __restrict__ W_hh,
    u16* __restrict__ hi, u16* __restrict__ lo)
{
  const int idx = blockIdx.x * 256 + threadIdx.x;
  if (idx >= NGATE * KPAD) return;
  const int n = idx / KPAD;
  const int k = idx - n * KPAD;
  float v = 0.f;
  if (k < 3 * DIN)       v = W_ih[(size_t)n * (3 * DIN) + k];
  else if (k >= VOFF)    v = W_hh[(size_t)n * HDIM + (k - VOFF)];
  split_store(v, &hi[idx], &lo[idx]);
}

__global__ __launch_bounds__(256) void pack_watt(
    const float* __restrict__ W_att,   // [3][H][L]
    u16* __restrict__ hi, u16* __restrict__ lo)
{
  const int idx = blockIdx.x * 256 + threadIdx.x;   // [384][768]
  if (idx >= 384 * HDIM) return;
  const int n = idx / HDIM;          // n = k*128 + l
  const int h = idx - n * HDIM;
  const int katt = n >> 7;
  const int l = n & 127;
  const float v = W_att[((size_t)katt * HDIM + h) * LSEQ + l];
  split_store(v, &hi[idx], &lo[idx]);
}

__global__ __launch_bounds__(256) void init_state(
    u16* __restrict__ act_hi, u16* __restrict__ act_lo,
    float* __restrict__ cst, float* __restrict__ hmax)
{
  const int idx = blockIdx.x * 256 + threadIdx.x;
  if (idx < B_SZ * KPAD) { act_hi[idx] = 0; act_lo[idx] = 0; }
  if (idx < B_SZ * HDIM) { cst[idx] = 0.f; hmax[idx] = -3.4e38f; }
}

// ---------------------------------------------------------------------------
extern "C" void kernel_launch(void* const* d_in, const int* in_sizes, int n_in,
                              void* d_out, int out_size, void* d_ws, size_t ws_size,
                              hipStream_t stream) {
  const float* X     = (const float*)d_in[0];
  const float* Fe    = (const float*)d_in[1];
  const float* W_att = (const float*)d_in[2];
  const float* b_att = (const float*)d_in[3];
  const float* W_ih  = (const float*)d_in[4];
  const float* W_hh  = (const float*)d_in[5];
  const float* b_ih  = (const float*)d_in[6];
  const float* b_hh  = (const float*)d_in[7];
  const float* W_d1  = (const float*)d_in[8];
  const float* b_d1  = (const float*)d_in[9];
  const float* W_r   = (const float*)d_in[10];
  const float* b_r   = (const float*)d_in[11];
  const float* W_a   = (const float*)d_in[12];
  const float* W_d2  = (const float*)d_in[13];
  const float* b_d2  = (const float*)d_in[14];
  float* out = (float*)d_out;

  char* base = (char*)d_ws;
  size_t off = 0;
  auto alloc = [&](size_t nbytes) -> void* {
    void* p = base + off;
    off = (off + nbytes + 255) & ~(size_t)255;
    return p;
  };
  u16* act_hi  = (u16*)alloc((size_t)B_SZ * KPAD * 2);
  u16* act_lo  = (u16*)alloc((size_t)B_SZ * KPAD * 2);
  u16* wcat_hi = (u16*)alloc((size_t)NGATE * KPAD * 2);
  u16* wcat_lo = (u16*)alloc((size_t)NGATE * KPAD * 2);
  u16* watt_hi = (u16*)alloc((size_t)384 * HDIM * 2);
  u16* watt_lo = (u16*)alloc((size_t)384 * HDIM * 2);
  float* logits = (float*)alloc((size_t)B_SZ * 384 * 4);
  float* gates  = (float*)alloc((size_t)B_SZ * NGATE * 4);
  float* cst    = (float*)alloc((size_t)B_SZ * HDIM * 4);
  float* hmax   = (float*)alloc((size_t)B_SZ * HDIM * 4);

  pack_wcat<<<(NGATE * KPAD + 255) / 256, 256, 0, stream>>>(W_ih, W_hh, wcat_hi, wcat_lo);
  pack_watt<<<(384 * HDIM + 255) / 256, 256, 0, stream>>>(W_att, watt_hi, watt_lo);
  init_state<<<(B_SZ * KPAD + 255) / 256, 256, 0, stream>>>(act_hi, act_lo, cst, hmax);

  for (int step = 0; step < LSEQ; ++step) {
    // logits = h @ W_att_T^T : A = act[:, VOFF:VOFF+768]
    gemm_split3<64, 64><<<dim3(B_SZ / 64, 384 / 64), 256, 0, stream>>>(
        act_hi + VOFF, act_lo + VOFF, KPAD, watt_hi, watt_lo, HDIM,
        logits, 384, HDIM / 32);
    softmax_v<<<B_SZ, 512, 0, stream>>>(logits, b_att, X, act_hi, act_lo);
    // gates = [v,h] @ Wcat^T
    gemm_split3<128, 128><<<dim3(B_SZ / 128, NGATE / 128), 256, 0, stream>>>(
        act_hi, act_lo, KPAD, wcat_hi, wcat_lo, KPAD,
        gates, NGATE, KPAD / 32);
    lstm_update<<<(B_SZ * HDIM) / 256, 256, 0, stream>>>(
        gates, b_ih, b_hh, cst, hmax, act_hi, act_lo);
  }

  final_head<<<B_SZ, 64, 0, stream>>>(hmax, Fe, W_d1, b_d1, W_r, b_r, W_a, W_d2, b_d2, out);
}

// Round 2
// 14946.100 us; speedup vs baseline: 1.0011x; 1.0011x over previous
//
#include <hip/hip_runtime.h>
#include <stdint.h>

// ---------------------------------------------------------------------------
// LstmAtt: 128-step LSTM+attention recurrence, B=1024, H=768, D_IN=130, L=128.
// Round-1 design: correctness-first with split-bf16 (hi+lo) MFMA GEMMs
// (3-term product => ~fp32 accuracy), fp32 softmax / v-sum / LSTM / head.
// Act buffer layout per row (K = 1184 halfs): [0..389]=v (3*130), [390..415]=0 pad
// (16B alignment for the h sub-GEMM), [416..1183]=h (768).
// ---------------------------------------------------------------------------

#define B_SZ   1024
#define LSEQ   128
#define DIN    130
#define HDIM   768
#define NFEAT  49
#define NPROJ  40
#define KPAD   1184
#define VOFF   416
#define NGATE  3072

typedef unsigned short u16;
typedef __attribute__((ext_vector_type(8))) short short8;
typedef __attribute__((ext_vector_type(4))) float f32x4;

__device__ __forceinline__ u16 f2bf(float f) {
  unsigned int u = __float_as_uint(f);
  u += 0x7FFFu + ((u >> 16) & 1u);   // round-to-nearest-even
  return (u16)(u >> 16);
}
__device__ __forceinline__ float bf2f(u16 b) {
  return __uint_as_float(((unsigned int)b) << 16);
}
__device__ __forceinline__ void split_store(float x, u16* hi, u16* lo) {
  u16 h = f2bf(x);
  *hi = h;
  *lo = f2bf(x - bf2f(h));
}

// ---------------------------------------------------------------------------
// Split-bf16 GEMM:  C[M,N] = A[M,K] * W[N,K]^T   (both stored row-major, K-pad mult 32)
// A,W given as bf16 hi/lo pairs; 3 MFMA terms: hi*hi + lo*hi + hi*lo.
// Block = 256 thr (4 waves, 2x2), tile BM x BN, per-wave (BM/2)x(BN/2) of 16x16 frags.
// LDS row stride 40 halfs (80 B): 16B-aligned, m and m+8 alias 2-way only (free).
// mfma_f32_16x16x32_bf16 layouts (HW-verified per guide):
//   A frag: A[m=lane&15][k=quad*8+j]; B frag: W[n=lane&15][k=quad*8+j];
//   C/D:    col=lane&15, row=quad*4+reg.
// ---------------------------------------------------------------------------
template<int BM, int BN>
__global__ __launch_bounds__(256, 2) void gemm_split3(
    const u16* __restrict__ Ahi, const u16* __restrict__ Alo, int lda,
    const u16* __restrict__ Whi, const u16* __restrict__ Wlo, int ldw,
    float* __restrict__ C, int ldc, int ktiles)
{
  constexpr int FM = BM / 32;
  constexpr int FN = BN / 32;
  constexpr int STR = 40;
  __shared__ __align__(16) u16 sAh[BM * STR];
  __shared__ __align__(16) u16 sAl[BM * STR];
  __shared__ __align__(16) u16 sBh[BN * STR];
  __shared__ __align__(16) u16 sBl[BN * STR];

  const int tid  = threadIdx.x;
  const int lane = tid & 63;
  const int wid  = tid >> 6;
  const int wm   = (wid & 1) * (BM / 2);
  const int wn   = (wid >> 1) * (BN / 2);
  const int lm   = lane & 15;
  const int quad = lane >> 4;
  const long bm  = (long)blockIdx.x * BM;
  const long bn  = (long)blockIdx.y * BN;

  f32x4 acc[FM][FN];
#pragma unroll
  for (int i = 0; i < FM; ++i)
#pragma unroll
    for (int j = 0; j < FN; ++j)
      acc[i][j] = (f32x4){0.f, 0.f, 0.f, 0.f};

  for (int kt = 0; kt < ktiles; ++kt) {
    const int k0 = kt * 32;
    __syncthreads();
#pragma unroll
    for (int i = tid; i < BM * 4; i += 256) {
      const int r = i >> 2, c = (i & 3) * 8;
      const size_t g = (size_t)(bm + r) * lda + k0 + c;
      *(uint4*)&sAh[r * STR + c] = *(const uint4*)(Ahi + g);
      *(uint4*)&sAl[r * STR + c] = *(const uint4*)(Alo + g);
    }
#pragma unroll
    for (int i = tid; i < BN * 4; i += 256) {
      const int r = i >> 2, c = (i & 3) * 8;
      const size_t g = (size_t)(bn + r) * ldw + k0 + c;
      *(uint4*)&sBh[r * STR + c] = *(const uint4*)(Whi + g);
      *(uint4*)&sBl[r * STR + c] = *(const uint4*)(Wlo + g);
    }
    __syncthreads();

    short8 ah[FM], al[FM], bh[FN], bl[FN];
#pragma unroll
    for (int mi = 0; mi < FM; ++mi) {
      const int row = wm + mi * 16 + lm;
      ah[mi] = *(const short8*)&sAh[row * STR + quad * 8];
      al[mi] = *(const short8*)&sAl[row * STR + quad * 8];
    }
#pragma unroll
    for (int ni = 0; ni < FN; ++ni) {
      const int row = wn + ni * 16 + lm;
      bh[ni] = *(const short8*)&sBh[row * STR + quad * 8];
      bl[ni] = *(const short8*)&sBl[row * STR + quad * 8];
    }
#pragma unroll
    for (int mi = 0; mi < FM; ++mi)
#pragma unroll
      for (int ni = 0; ni < FN; ++ni) {
        acc[mi][ni] = __builtin_amdgcn_mfma_f32_16x16x32_bf16(ah[mi], bh[ni], acc[mi][ni], 0, 0, 0);
        acc[mi][ni] = __builtin_amdgcn_mfma_f32_16x16x32_bf16(al[mi], bh[ni], acc[mi][ni], 0, 0, 0);
        acc[mi][ni] = __builtin_amdgcn_mfma_f32_16x16x32_bf16(ah[mi], bl[ni], acc[mi][ni], 0, 0, 0);
      }
  }

#pragma unroll
  for (int mi = 0; mi < FM; ++mi)
#pragma unroll
    for (int ni = 0; ni < FN; ++ni) {
      const long col = bn + wn + ni * 16 + lm;
#pragma unroll
      for (int r = 0; r < 4; ++r) {
        const long row = bm + wm + mi * 16 + quad * 4 + r;
        C[(size_t)row * ldc + col] = acc[mi][ni][r];
      }
    }
}

// ---------------------------------------------------------------------------
// Per-sample softmax over L (x3 heads) + v = alp @ X[b]; writes v into act hi/lo.
// Block = 512 thr per sample. Phase 1: t<384 -> (k=t>>7, l=t&127). Phase 2:
// t<390 -> (k=t/130, d=t%130), column-coalesced X reads.
// ---------------------------------------------------------------------------
__global__ __launch_bounds__(512) void softmax_v(
    const float* __restrict__ logits,   // [B][384] = [b][k*128+l]
    const float* __restrict__ b_att,    // [3][128]
    const float* __restrict__ X,        // [B][128][130]
    u16* __restrict__ act_hi, u16* __restrict__ act_lo)
{
  const int b = blockIdx.x;
  const int t = threadIdx.x;
  __shared__ float s_val[384];
  __shared__ float s_red[512];

  float x = -3.4e38f;
  if (t < 384) {
    x = logits[(size_t)b * 384 + t] + b_att[t];
    s_val[t] = x;
  }
  s_red[t] = x;
  __syncthreads();
#pragma unroll
  for (int off = 64; off > 0; off >>= 1) {
    float other = -3.4e38f;
    if ((t & 127) < off) other = s_red[t + off];
    __syncthreads();
    if ((t & 127) < off) s_red[t] = fmaxf(s_red[t], other);
    __syncthreads();
  }
  const float mk = s_red[t & ~127];
  __syncthreads();

  float e = 0.f;
  if (t < 384) e = expf(s_val[t] - mk);
  s_red[t] = e;
  __syncthreads();
#pragma unroll
  for (int off = 64; off > 0; off >>= 1) {
    float other = 0.f;
    if ((t & 127) < off) other = s_red[t + off];
    __syncthreads();
    if ((t & 127) < off) s_red[t] += other;
    __syncthreads();
  }
  const float sk = s_red[t & ~127];
  if (t < 384) s_val[t] = e / sk;     // normalized alp
  __syncthreads();

  if (t < 390) {
    const int k = t / 130;
    const int d = t - k * 130;
    const float* __restrict__ Xb = X + (size_t)b * LSEQ * DIN + d;
    const float* __restrict__ ak = s_val + k * 128;
    float acc = 0.f;
#pragma unroll 8
    for (int l = 0; l < LSEQ; ++l) acc += ak[l] * Xb[(size_t)l * DIN];
    const size_t o = (size_t)b * KPAD + t;   // col = k*130+d = t
    split_store(acc, &act_hi[o], &act_lo[o]);
  }
}

// ---------------------------------------------------------------------------
// LSTM pointwise: gates [B][3072] (i,f,g,o) + biases -> c,h update; running max;
// writes h into act hi/lo at column VOFF.
// ---------------------------------------------------------------------------
__global__ __launch_bounds__(256) void lstm_update(
    const float* __restrict__ gates,
    const float* __restrict__ b_ih, const float* __restrict__ b_hh,
    float* __restrict__ cst, float* __restrict__ hmax,
    u16* __restrict__ act_hi, u16* __restrict__ act_lo)
{
  const int idx = blockIdx.x * 256 + threadIdx.x;       // B*H
  const int b = idx / HDIM;
  const int j = idx - b * HDIM;
  const float* g = gates + (size_t)b * NGATE;
  const float gi = g[j]        + b_ih[j]        + b_hh[j];
  const float gf = g[768 + j]  + b_ih[768 + j]  + b_hh[768 + j];
  const float gg = g[1536 + j] + b_ih[1536 + j] + b_hh[1536 + j];
  const float go = g[2304 + j] + b_ih[2304 + j] + b_hh[2304 + j];
  const float si = 1.f / (1.f + expf(-gi));
  const float sf = 1.f / (1.f + expf(-gf));
  const float so = 1.f / (1.f + expf(-go));
  const float cn = sf * cst[idx] + si * tanhf(gg);
  const float hn = so * tanhf(cn);
  cst[idx] = cn;
  hmax[idx] = fmaxf(hmax[idx], hn);
  const size_t o = (size_t)b * KPAD + VOFF + j;
  split_store(hn, &act_hi[o], &act_lo[o]);
}

// ---------------------------------------------------------------------------
// Final head (once): y=relu(hmax@Wd1^T+b); r1/r2=leaky(.@Wr^T+b); a=softmax(tanh(r)@Wa);
// s=relu(a0*r1+a1*r2); out=s@Wd2^T+b. One 64-thread block per sample (tiny).
// ---------------------------------------------------------------------------
__global__ __launch_bounds__(64) void final_head(
    const float* __restrict__ hmax, const float* __restrict__ Fe,
    const float* __restrict__ W_d1, const float* __restrict__ b_d1,
    const float* __restrict__ W_r,  const float* __restrict__ b_r,
    const float* __restrict__ W_a,
    const float* __restrict__ W_d2, const float* __restrict__ b_d2,
    float* __restrict__ out)
{
  const int b = blockIdx.x;
  const int t = threadIdx.x;
  __shared__ float sx[HDIM];
  __shared__ float sy[NFEAT];
  __shared__ float sr1[NPROJ], sr2[NPROJ];
  __shared__ float sa[2];

  for (int i = t; i < HDIM; i += 64) sx[i] = hmax[(size_t)b * HDIM + i];
  __syncthreads();

  if (t < NFEAT) {
    float acc = b_d1[t];
    const float* w = W_d1 + (size_t)t * HDIM;
    for (int i = 0; i < HDIM; ++i) acc += sx[i] * w[i];
    sy[t] = fmaxf(acc, 0.f);
  }
  __syncthreads();

  if (t < NPROJ) {
    float a1 = b_r[t], a2 = b_r[t];
    const float* w  = W_r + (size_t)t * NFEAT;
    const float* fe = Fe + (size_t)b * NFEAT;
    for (int i = 0; i < NFEAT; ++i) { a1 += sy[i] * w[i]; a2 += fe[i] * w[i]; }
    sr1[t] = (a1 > 0.f) ? a1 : 0.01f * a1;   // jax.nn.leaky_relu default slope
    sr2[t] = (a2 > 0.f) ? a2 : 0.01f * a2;
  }
  __syncthreads();

  if (t == 0) {
    float a1 = 0.f, a2 = 0.f;
    for (int p = 0; p < NPROJ; ++p) {
      a1 += tanhf(sr1[p]) * W_a[p];
      a2 += tanhf(sr2[p]) * W_a[p];
    }
    const float mx = fmaxf(a1, a2);
    const float e1 = expf(a1 - mx), e2 = expf(a2 - mx);
    sa[0] = e1 / (e1 + e2);
    sa[1] = e2 / (e1 + e2);
  }
  __syncthreads();

  if (t < 2) {
    float acc = b_d2[t];
    const float* w = W_d2 + (size_t)t * NPROJ;
    for (int p = 0; p < NPROJ; ++p) {
      float s = sa[0] * sr1[p] + sa[1] * sr2[p];
      s = fmaxf(s, 0.f);
      acc += s * w[p];
    }
    out[(size_t)b * 2 + t] = acc;
  }
}

// ---------------------------------------------------------------------------
// Setup kernels (run every launch; ws is re-poisoned by the harness).
// ---------------------------------------------------------------------------
__global__ __launch_bounds__(256) void pack_wcat(
    const float* __restrict__ W_ih, const float* __restrict__ W_hh,
    u16* __restrict__ hi, u16* __restrict__ lo)
{
  const int idx = blockIdx.x * 256 + threadIdx.x;
  if (idx >= NGATE * KPAD) return;
  const int n = idx / KPAD;
  const int k = idx - n * KPAD;
  float v = 0.f;
  if (k < 3 * DIN)       v = W_ih[(size_t)n * (3 * DIN) + k];
  else if (k >= VOFF)    v = W_hh[(size_t)n * HDIM + (k - VOFF)];
  split_store(v, &hi[idx], &lo[idx]);
}

__global__ __launch_bounds__(256) void pack_watt(
    const float* __restrict__ W_att,   // [3][H][L]
    u16* __restrict__ hi, u16* __restrict__ lo)
{
  const int idx = blockIdx.x * 256 + threadIdx.x;   // [384][768]
  if (idx >= 384 * HDIM) return;
  const int n = idx / HDIM;          // n = k*128 + l
  const int h = idx - n * HDIM;
  const int katt = n >> 7;
  const int l = n & 127;
  const float v = W_att[((size_t)katt * HDIM + h) * LSEQ + l];
  split_store(v, &hi[idx], &lo[idx]);
}

__global__ __launch_bounds__(256) void init_state(
    u16* __restrict__ act_hi, u16* __restrict__ act_lo,
    float* __restrict__ cst, float* __restrict__ hmax)
{
  const int idx = blockIdx.x * 256 + threadIdx.x;
  if (idx < B_SZ * KPAD) { act_hi[idx] = 0; act_lo[idx] = 0; }
  if (idx < B_SZ * HDIM) { cst[idx] = 0.f; hmax[idx] = -3.4e38f; }
}

// ---------------------------------------------------------------------------
extern "C" void kernel_launch(void* const* d_in, const int* in_sizes, int n_in,
                              void* d_out, int out_size, void* d_ws, size_t ws_size,
                              hipStream_t stream) {
  const float* X     = (const float*)d_in[0];
  const float* Fe    = (const float*)d_in[1];
  const float* W_att = (const float*)d_in[2];
  const float* b_att = (const float*)d_in[3];
  const float* W_ih  = (const float*)d_in[4];
  const float* W_hh  = (const float*)d_in[5];
  const float* b_ih  = (const float*)d_in[6];
  const float* b_hh  = (const float*)d_in[7];
  const float* W_d1  = (const float*)d_in[8];
  const float* b_d1  = (const float*)d_in[9];
  const float* W_r   = (const float*)d_in[10];
  const float* b_r   = (const float*)d_in[11];
  const float* W_a   = (const float*)d_in[12];
  const float* W_d2  = (const float*)d_in[13];
  const float* b_d2  = (const float*)d_in[14];
  float* out = (float*)d_out;

  char* base = (char*)d_ws;
  size_t off = 0;
  auto alloc = [&](size_t nbytes) -> void* {
    void* p = base + off;
    off = (off + nbytes + 255) & ~(size_t)255;
    return p;
  };
  u16* act_hi  = (u16*)alloc((size_t)B_SZ * KPAD * 2);
  u16* act_lo  = (u16*)alloc((size_t)B_SZ * KPAD * 2);
  u16* wcat_hi = (u16*)alloc((size_t)NGATE * KPAD * 2);
  u16* wcat_lo = (u16*)alloc((size_t)NGATE * KPAD * 2);
  u16* watt_hi = (u16*)alloc((size_t)384 * HDIM * 2);
  u16* watt_lo = (u16*)alloc((size_t)384 * HDIM * 2);
  float* logits = (float*)alloc((size_t)B_SZ * 384 * 4);
  float* gates  = (float*)alloc((size_t)B_SZ * NGATE * 4);
  float* cst    = (float*)alloc((size_t)B_SZ * HDIM * 4);
  float* hmax   = (float*)alloc((size_t)B_SZ * HDIM * 4);

  pack_wcat<<<(NGATE * KPAD + 255) / 256, 256, 0, stream>>>(W_ih, W_hh, wcat_hi, wcat_lo);
  pack_watt<<<(384 * HDIM + 255) / 256, 256, 0, stream>>>(W_att, watt_hi, watt_lo);
  init_state<<<(B_SZ * KPAD + 255) / 256, 256, 0, stream>>>(act_hi, act_lo, cst, hmax);

  for (int step = 0; step < LSEQ; ++step) {
    // logits = h @ W_att_T^T : A = act[:, VOFF:VOFF+768]
    gemm_split3<64, 64><<<dim3(B_SZ / 64, 384 / 64), 256, 0, stream>>>(
        act_hi + VOFF, act_lo + VOFF, KPAD, watt_hi, watt_lo, HDIM,
        logits, 384, HDIM / 32);
    softmax_v<<<B_SZ, 512, 0, stream>>>(logits, b_att, X, act_hi, act_lo);
    // gates = [v,h] @ Wcat^T
    gemm_split3<128, 128><<<dim3(B_SZ / 128, NGATE / 128), 256, 0, stream>>>(
        act_hi, act_lo, KPAD, wcat_hi, wcat_lo, KPAD,
        gates, NGATE, KPAD / 32);
    lstm_update<<<(B_SZ * HDIM) / 256, 256, 0, stream>>>(
        gates, b_ih, b_hh, cst, hmax, act_hi, act_lo);
  }

  final_head<<<B_SZ, 64, 0, stream>>>(hmax, Fe, W_d1, b_d1, W_r, b_r, W_a, W_d2, b_d2, out);
}

// Round 3
// 7581.145 us; speedup vs baseline: 1.9736x; 1.9715x over previous
//
#include <hip/hip_runtime.h>
#include <stdint.h>

// ---------------------------------------------------------------------------
// LstmAtt round 3: split-2 bf16 MFMA GEMMs (A = hi+lo exact, B = bf16 hi only),
// LSTM pointwise fused into gates-GEMM epilogue, global->VGPR prefetch
// double-buffering, bigger grids.
// Act row layout (KPAD=1184 halfs): [0..389]=v, [390..415]=0 pad, [416..1183]=h.
// Gates weights gathered per-block in 4 gate-strips of 32 j each.
// ---------------------------------------------------------------------------

#define B_SZ   1024
#define LSEQ   128
#define DIN    130
#define HDIM   768
#define NFEAT  49
#define NPROJ  40
#define KPAD   1184
#define VOFF   416
#define NGATE  3072
#define KT_G   37      // KPAD/32
#define KT_L   24      // HDIM/32

typedef unsigned short u16;
typedef __attribute__((ext_vector_type(8))) short short8;
typedef __attribute__((ext_vector_type(4))) float f32x4;

__device__ __forceinline__ u16 f2bf(float f) {
  unsigned int u = __float_as_uint(f);
  u += 0x7FFFu + ((u >> 16) & 1u);   // round-to-nearest-even
  return (u16)(u >> 16);
}
__device__ __forceinline__ float bf2f(u16 b) {
  return __uint_as_float(((unsigned int)b) << 16);
}
__device__ __forceinline__ void split_store(float x, u16* hi, u16* lo) {
  u16 h = f2bf(x);
  *hi = h;
  *lo = f2bf(x - bf2f(h));
}

// ---------------------------------------------------------------------------
// Logits GEMM: C[1024,384] = h[1024,768] @ Watt[384,768]^T, split-2.
// BM=32, BN=64, 256 thr (4 waves 2x2: wave tile 16x32). Grid (32,6)=192.
// LDS stride 40 halfs: 16B aligned, 2-way bank alias only (free).
// ---------------------------------------------------------------------------
__global__ __launch_bounds__(256, 2) void gemm_logits(
    const u16* __restrict__ Ahi, const u16* __restrict__ Alo,
    const u16* __restrict__ Bh, float* __restrict__ C)
{
  __shared__ __align__(16) u16 sAh[32 * 40];
  __shared__ __align__(16) u16 sAl[32 * 40];
  __shared__ __align__(16) u16 sBh[64 * 40];

  const int tid = threadIdx.x, lane = tid & 63, wid = tid >> 6;
  const int wm = (wid & 1) * 16, wn = (wid >> 1) * 32;
  const int lm = lane & 15, quad = lane >> 4;
  const int bm = blockIdx.x * 32, bn = blockIdx.y * 64;

  const bool aload = tid < 128;
  const int ar = tid >> 2, ac = (tid & 3) * 8;   // ar in [0,64); A uses [0,32)
  const size_t a_off = (size_t)(bm + ar) * KPAD + ac;
  const size_t b_off = (size_t)(bn + ar) * HDIM + ac;

  uint4 ph, pl, pb;
  if (aload) {
    ph = *(const uint4*)(Ahi + a_off);
    pl = *(const uint4*)(Alo + a_off);
  }
  pb = *(const uint4*)(Bh + b_off);

  f32x4 acc0 = {0.f, 0.f, 0.f, 0.f}, acc1 = {0.f, 0.f, 0.f, 0.f};

  for (int kt = 0; kt < KT_L; ++kt) {
    if (aload) {
      *(uint4*)&sAh[ar * 40 + ac] = ph;
      *(uint4*)&sAl[ar * 40 + ac] = pl;
    }
    *(uint4*)&sBh[ar * 40 + ac] = pb;
    __syncthreads();
    if (kt + 1 < KT_L) {
      const int k0 = (kt + 1) * 32;
      if (aload) {
        ph = *(const uint4*)(Ahi + a_off + k0);
        pl = *(const uint4*)(Alo + a_off + k0);
      }
      pb = *(const uint4*)(Bh + b_off + k0);
    }
    const short8 ah = *(const short8*)&sAh[(wm + lm) * 40 + quad * 8];
    const short8 al = *(const short8*)&sAl[(wm + lm) * 40 + quad * 8];
    const short8 b0 = *(const short8*)&sBh[(wn + lm) * 40 + quad * 8];
    const short8 b1 = *(const short8*)&sBh[(wn + 16 + lm) * 40 + quad * 8];
    acc0 = __builtin_amdgcn_mfma_f32_16x16x32_bf16(ah, b0, acc0, 0, 0, 0);
    acc0 = __builtin_amdgcn_mfma_f32_16x16x32_bf16(al, b0, acc0, 0, 0, 0);
    acc1 = __builtin_amdgcn_mfma_f32_16x16x32_bf16(ah, b1, acc1, 0, 0, 0);
    acc1 = __builtin_amdgcn_mfma_f32_16x16x32_bf16(al, b1, acc1, 0, 0, 0);
    __syncthreads();
  }

  const int col = bn + wn + lm;
  const int row0 = bm + wm + quad * 4;
#pragma unroll
  for (int r = 0; r < 4; ++r) {
    C[(size_t)(row0 + r) * 384 + col]      = acc0[r];
    C[(size_t)(row0 + r) * 384 + col + 16] = acc1[r];
  }
}

// ---------------------------------------------------------------------------
// Gates GEMM + fused LSTM: pre[1024,128-strip] = act[1024,1184] @ Wstrip^T,
// split-2. BM=64, BN=128 (4 gate-strips of 32 j), 256 thr (waves 2x2: 32x64).
// Grid (16,24)=384. Epilogue: C -> LDS fp32 tile (stride 132, 2-way only) ->
// per-(b,j) LSTM update, h split-stored into act, c/hmax updated.
// ---------------------------------------------------------------------------
__global__ __launch_bounds__(256, 2) void gemm_gates_lstm(
    const u16* __restrict__ Ahi, const u16* __restrict__ Alo,
    const u16* __restrict__ Wh,  const float* __restrict__ bsum,
    float* __restrict__ cst, float* __restrict__ hmax,
    u16* __restrict__ act_hi, u16* __restrict__ act_lo)
{
  __shared__ __align__(16) char smem[64 * 132 * 4];   // 33792 B union
  u16* sAh = (u16*)smem;                 //  5120 B (64*40 halfs)
  u16* sAl = (u16*)(smem + 5120);        //  5120 B
  u16* sBh = (u16*)(smem + 10240);       // 10240 B (128*40 halfs)
  float* tile = (float*)smem;            // epilogue: 64 x 132 fp32

  const int tid = threadIdx.x, lane = tid & 63, wid = tid >> 6;
  const int wm = (wid & 1) * 32, wn = (wid >> 1) * 64;
  const int lm = lane & 15, quad = lane >> 4;
  const int bm = blockIdx.x * 64, j0 = blockIdx.y * 32;

  const int ar = tid >> 2, ac = (tid & 3) * 8;   // ar in [0,64)
  const size_t a_off = (size_t)(bm + ar) * KPAD + ac;
  const int br0 = ar, br1 = 64 + ar;
  const int n0 = (br0 >> 5) * HDIM + j0 + (br0 & 31);   // gate strip gather
  const int n1 = (br1 >> 5) * HDIM + j0 + (br1 & 31);
  const size_t b_off0 = (size_t)n0 * KPAD + ac;
  const size_t b_off1 = (size_t)n1 * KPAD + ac;

  uint4 ph, pl, pb0, pb1;
  ph  = *(const uint4*)(Ahi + a_off);
  pl  = *(const uint4*)(Alo + a_off);
  pb0 = *(const uint4*)(Wh + b_off0);
  pb1 = *(const uint4*)(Wh + b_off1);

  f32x4 acc[2][4];
#pragma unroll
  for (int mi = 0; mi < 2; ++mi)
#pragma unroll
    for (int ni = 0; ni < 4; ++ni)
      acc[mi][ni] = (f32x4){0.f, 0.f, 0.f, 0.f};

  for (int kt = 0; kt < KT_G; ++kt) {
    *(uint4*)&sAh[ar * 40 + ac]  = ph;
    *(uint4*)&sAl[ar * 40 + ac]  = pl;
    *(uint4*)&sBh[br0 * 40 + ac] = pb0;
    *(uint4*)&sBh[br1 * 40 + ac] = pb1;
    __syncthreads();
    if (kt + 1 < KT_G) {
      const int k0 = (kt + 1) * 32;
      ph  = *(const uint4*)(Ahi + a_off + k0);
      pl  = *(const uint4*)(Alo + a_off + k0);
      pb0 = *(const uint4*)(Wh + b_off0 + k0);
      pb1 = *(const uint4*)(Wh + b_off1 + k0);
    }
    short8 ah[2], al[2], bh[4];
#pragma unroll
    for (int mi = 0; mi < 2; ++mi) {
      ah[mi] = *(const short8*)&sAh[(wm + mi * 16 + lm) * 40 + quad * 8];
      al[mi] = *(const short8*)&sAl[(wm + mi * 16 + lm) * 40 + quad * 8];
    }
#pragma unroll
    for (int ni = 0; ni < 4; ++ni)
      bh[ni] = *(const short8*)&sBh[(wn + ni * 16 + lm) * 40 + quad * 8];
#pragma unroll
    for (int mi = 0; mi < 2; ++mi)
#pragma unroll
      for (int ni = 0; ni < 4; ++ni) {
        acc[mi][ni] = __builtin_amdgcn_mfma_f32_16x16x32_bf16(ah[mi], bh[ni], acc[mi][ni], 0, 0, 0);
        acc[mi][ni] = __builtin_amdgcn_mfma_f32_16x16x32_bf16(al[mi], bh[ni], acc[mi][ni], 0, 0, 0);
      }
    __syncthreads();
  }

  // ---- epilogue: C frags -> LDS fp32 tile (cols: 4 gate strips of 32 j) ----
#pragma unroll
  for (int mi = 0; mi < 2; ++mi)
#pragma unroll
    for (int ni = 0; ni < 4; ++ni) {
      const int c = wn + ni * 16 + lm;
#pragma unroll
      for (int r = 0; r < 4; ++r)
        tile[(wm + mi * 16 + quad * 4 + r) * 132 + c] = acc[mi][ni][r];
    }
  __syncthreads();

#pragma unroll
  for (int i = 0; i < 8; ++i) {
    const int lin = tid + 256 * i;      // over 64*32 (row, jj)
    const int row = lin >> 5, jj = lin & 31;
    const int b = bm + row, j = j0 + jj;
    const float* tr = tile + row * 132;
    const float pi = tr[jj]      + bsum[j];
    const float pf = tr[32 + jj] + bsum[HDIM + j];
    const float pg = tr[64 + jj] + bsum[2 * HDIM + j];
    const float po = tr[96 + jj] + bsum[3 * HDIM + j];
    const float si = 1.f / (1.f + expf(-pi));
    const float sf = 1.f / (1.f + expf(-pf));
    const float so = 1.f / (1.f + expf(-po));
    const size_t cidx = (size_t)b * HDIM + j;
    const float cn = sf * cst[cidx] + si * tanhf(pg);
    const float hn = so * tanhf(cn);
    cst[cidx] = cn;
    hmax[cidx] = fmaxf(hmax[cidx], hn);
    const size_t o = (size_t)b * KPAD + VOFF + j;
    split_store(hn, &act_hi[o], &act_lo[o]);
  }
}

// ---------------------------------------------------------------------------
// Per-sample softmax over L (x3 heads) + v = alp @ X[b]; writes v into act.
// ---------------------------------------------------------------------------
__global__ __launch_bounds__(512) void softmax_v(
    const float* __restrict__ logits,   // [B][384] = [b][k*128+l]
    const float* __restrict__ b_att,    // [3][128]
    const float* __restrict__ X,        // [B][128][130]
    u16* __restrict__ act_hi, u16* __restrict__ act_lo)
{
  const int b = blockIdx.x;
  const int t = threadIdx.x;
  __shared__ float s_val[384];
  __shared__ float s_red[512];

  float x = -3.4e38f;
  if (t < 384) {
    x = logits[(size_t)b * 384 + t] + b_att[t];
    s_val[t] = x;
  }
  s_red[t] = x;
  __syncthreads();
#pragma unroll
  for (int off = 64; off > 0; off >>= 1) {
    float other = -3.4e38f;
    if ((t & 127) < off) other = s_red[t + off];
    __syncthreads();
    if ((t & 127) < off) s_red[t] = fmaxf(s_red[t], other);
    __syncthreads();
  }
  const float mk = s_red[t & ~127];
  __syncthreads();

  float e = 0.f;
  if (t < 384) e = expf(s_val[t] - mk);
  s_red[t] = e;
  __syncthreads();
#pragma unroll
  for (int off = 64; off > 0; off >>= 1) {
    float other = 0.f;
    if ((t & 127) < off) other = s_red[t + off];
    __syncthreads();
    if ((t & 127) < off) s_red[t] += other;
    __syncthreads();
  }
  const float sk = s_red[t & ~127];
  if (t < 384) s_val[t] = e / sk;     // normalized alp
  __syncthreads();

  if (t < 390) {
    const int k = t / 130;
    const int d = t - k * 130;
    const float* __restrict__ Xb = X + (size_t)b * LSEQ * DIN + d;
    const float* __restrict__ ak = s_val + k * 128;
    float acc = 0.f;
#pragma unroll 8
    for (int l = 0; l < LSEQ; ++l) acc += ak[l] * Xb[(size_t)l * DIN];
    const size_t o = (size_t)b * KPAD + t;
    split_store(acc, &act_hi[o], &act_lo[o]);
  }
}

// ---------------------------------------------------------------------------
// Final head (once per call).
// ---------------------------------------------------------------------------
__global__ __launch_bounds__(64) void final_head(
    const float* __restrict__ hmax, const float* __restrict__ Fe,
    const float* __restrict__ W_d1, const float* __restrict__ b_d1,
    const float* __restrict__ W_r,  const float* __restrict__ b_r,
    const float* __restrict__ W_a,
    const float* __restrict__ W_d2, const float* __restrict__ b_d2,
    float* __restrict__ out)
{
  const int b = blockIdx.x;
  const int t = threadIdx.x;
  __shared__ float sx[HDIM];
  __shared__ float sy[NFEAT];
  __shared__ float sr1[NPROJ], sr2[NPROJ];
  __shared__ float sa[2];

  for (int i = t; i < HDIM; i += 64) sx[i] = hmax[(size_t)b * HDIM + i];
  __syncthreads();

  if (t < NFEAT) {
    float acc = b_d1[t];
    const float* w = W_d1 + (size_t)t * HDIM;
    for (int i = 0; i < HDIM; ++i) acc += sx[i] * w[i];
    sy[t] = fmaxf(acc, 0.f);
  }
  __syncthreads();

  if (t < NPROJ) {
    float a1 = b_r[t], a2 = b_r[t];
    const float* w  = W_r + (size_t)t * NFEAT;
    const float* fe = Fe + (size_t)b * NFEAT;
    for (int i = 0; i < NFEAT; ++i) { a1 += sy[i] * w[i]; a2 += fe[i] * w[i]; }
    sr1[t] = (a1 > 0.f) ? a1 : 0.01f * a1;
    sr2[t] = (a2 > 0.f) ? a2 : 0.01f * a2;
  }
  __syncthreads();

  if (t == 0) {
    float a1 = 0.f, a2 = 0.f;
    for (int p = 0; p < NPROJ; ++p) {
      a1 += tanhf(sr1[p]) * W_a[p];
      a2 += tanhf(sr2[p]) * W_a[p];
    }
    const float mx = fmaxf(a1, a2);
    const float e1 = expf(a1 - mx), e2 = expf(a2 - mx);
    sa[0] = e1 / (e1 + e2);
    sa[1] = e2 / (e1 + e2);
  }
  __syncthreads();

  if (t < 2) {
    float acc = b_d2[t];
    const float* w = W_d2 + (size_t)t * NPROJ;
    for (int p = 0; p < NPROJ; ++p) {
      float s = sa[0] * sr1[p] + sa[1] * sr2[p];
      s = fmaxf(s, 0.f);
      acc += s * w[p];
    }
    out[(size_t)b * 2 + t] = acc;
  }
}

// ---------------------------------------------------------------------------
// Setup kernels (run every launch).
// ---------------------------------------------------------------------------
__global__ __launch_bounds__(256) void pack_w(
    const float* __restrict__ W_ih, const float* __restrict__ W_hh,
    const float* __restrict__ b_ih, const float* __restrict__ b_hh,
    u16* __restrict__ hi, float* __restrict__ bsum)
{
  const int idx = blockIdx.x * 256 + threadIdx.x;
  if (idx >= NGATE * KPAD) return;
  const int n = idx / KPAD;
  const int k = idx - n * KPAD;
  float v = 0.f;
  if (k < 3 * DIN)       v = W_ih[(size_t)n * (3 * DIN) + k];
  else if (k >= VOFF)    v = W_hh[(size_t)n * HDIM + (k - VOFF)];
  hi[idx] = f2bf(v);
  if (k == 0) bsum[n] = b_ih[n] + b_hh[n];
}

__global__ __launch_bounds__(256) void pack_watt(
    const float* __restrict__ W_att,   // [3][H][L]
    u16* __restrict__ hi)
{
  const int idx = blockIdx.x * 256 + threadIdx.x;   // [384][768]
  if (idx >= 384 * HDIM) return;
  const int n = idx / HDIM;          // n = k*128 + l
  const int h = idx - n * HDIM;
  const int katt = n >> 7;
  const int l = n & 127;
  hi[idx] = f2bf(W_att[((size_t)katt * HDIM + h) * LSEQ + l]);
}

__global__ __launch_bounds__(256) void init_state(
    u16* __restrict__ act_hi, u16* __restrict__ act_lo,
    float* __restrict__ cst, float* __restrict__ hmax)
{
  const int idx = blockIdx.x * 256 + threadIdx.x;
  if (idx < B_SZ * KPAD) { act_hi[idx] = 0; act_lo[idx] = 0; }
  if (idx < B_SZ * HDIM) { cst[idx] = 0.f; hmax[idx] = -3.4e38f; }
}

// ---------------------------------------------------------------------------
extern "C" void kernel_launch(void* const* d_in, const int* in_sizes, int n_in,
                              void* d_out, int out_size, void* d_ws, size_t ws_size,
                              hipStream_t stream) {
  const float* X     = (const float*)d_in[0];
  const float* Fe    = (const float*)d_in[1];
  const float* W_att = (const float*)d_in[2];
  const float* b_att = (const float*)d_in[3];
  const float* W_ih  = (const float*)d_in[4];
  const float* W_hh  = (const float*)d_in[5];
  const float* b_ih  = (const float*)d_in[6];
  const float* b_hh  = (const float*)d_in[7];
  const float* W_d1  = (const float*)d_in[8];
  const float* b_d1  = (const float*)d_in[9];
  const float* W_r   = (const float*)d_in[10];
  const float* b_r   = (const float*)d_in[11];
  const float* W_a   = (const float*)d_in[12];
  const float* W_d2  = (const float*)d_in[13];
  const float* b_d2  = (const float*)d_in[14];
  float* out = (float*)d_out;

  char* base = (char*)d_ws;
  size_t off = 0;
  auto alloc = [&](size_t nbytes) -> void* {
    void* p = base + off;
    off = (off + nbytes + 255) & ~(size_t)255;
    return p;
  };
  u16* act_hi  = (u16*)alloc((size_t)B_SZ * KPAD * 2);
  u16* act_lo  = (u16*)alloc((size_t)B_SZ * KPAD * 2);
  u16* wcat_hi = (u16*)alloc((size_t)NGATE * KPAD * 2);
  u16* watt_hi = (u16*)alloc((size_t)384 * HDIM * 2);
  float* bsum  = (float*)alloc((size_t)NGATE * 4);
  float* logits = (float*)alloc((size_t)B_SZ * 384 * 4);
  float* cst    = (float*)alloc((size_t)B_SZ * HDIM * 4);
  float* hmax   = (float*)alloc((size_t)B_SZ * HDIM * 4);

  pack_w<<<(NGATE * KPAD + 255) / 256, 256, 0, stream>>>(W_ih, W_hh, b_ih, b_hh, wcat_hi, bsum);
  pack_watt<<<(384 * HDIM + 255) / 256, 256, 0, stream>>>(W_att, watt_hi);
  init_state<<<(B_SZ * KPAD + 255) / 256, 256, 0, stream>>>(act_hi, act_lo, cst, hmax);

  for (int step = 0; step < LSEQ; ++step) {
    gemm_logits<<<dim3(B_SZ / 32, 384 / 64), 256, 0, stream>>>(
        act_hi + VOFF, act_lo + VOFF, watt_hi, logits);
    softmax_v<<<B_SZ, 512, 0, stream>>>(logits, b_att, X, act_hi, act_lo);
    gemm_gates_lstm<<<dim3(B_SZ / 64, NGATE / 128), 256, 0, stream>>>(
        act_hi, act_lo, wcat_hi, bsum, cst, hmax, act_hi, act_lo);
  }

  final_head<<<B_SZ, 64, 0, stream>>>(hmax, Fe, W_d1, b_d1, W_r, b_r, W_a, W_d2, b_d2, out);
}